// Round 2
// baseline (464.913 us; speedup 1.0000x reference)
//
#include <hip/hip_runtime.h>
#include <cstdint>
#include <cstddef>

typedef unsigned short u16;
typedef __attribute__((ext_vector_type(8))) short bf16x8;
typedef __attribute__((ext_vector_type(4))) float f32x4;

// ---------- bf16 helpers ----------
__device__ __forceinline__ float b2f(u16 u) {
  union { uint32_t i; float f; } x; x.i = ((uint32_t)u) << 16; return x.f;
}
__device__ __forceinline__ u16 f2b(float f) {
  union { float f; uint32_t i; } x; x.f = f;
  uint32_t u = x.i;
  u += 0x7fffu + ((u >> 16) & 1u);   // RNE
  return (u16)(u >> 16);
}

// load 8 consecutive elements (idx multiple of 8) as float, dtype-branched
__device__ __forceinline__ void load8(const void* p, size_t idx, bool f32, float o[8]) {
  if (f32) {
    const float4* fp = (const float4*)((const float*)p + idx);
    float4 x = fp[0], y = fp[1];
    o[0] = x.x; o[1] = x.y; o[2] = x.z; o[3] = x.w;
    o[4] = y.x; o[5] = y.y; o[6] = y.z; o[7] = y.w;
  } else {
    uint4 w = *(const uint4*)((const u16*)p + idx);
    uint32_t ww[4] = {w.x, w.y, w.z, w.w};
#pragma unroll
    for (int q = 0; q < 4; q++) {
      o[2 * q]     = b2f((u16)(ww[q] & 0xffffu));
      o[2 * q + 1] = b2f((u16)(ww[q] >> 16));
    }
  }
}
__device__ __forceinline__ void store8_bf16(u16* p, size_t idx, const float o[8]) {
  uint32_t w[4];
#pragma unroll
  for (int q = 0; q < 4; q++)
    w[q] = (uint32_t)f2b(o[2 * q]) | ((uint32_t)f2b(o[2 * q + 1]) << 16);
  *(uint4*)(p + idx) = make_uint4(w[0], w[1], w[2], w[3]);
}

// X swizzled index (u16 units): byte = row*1024 + ((col*2) ^ ((row&7)<<4))
// -> breaks the stride-1024B bank collision on af ds_read_b128 (2-way, free).
__device__ __forceinline__ int xidx(int row, int col) {
  return row * 512 + (col ^ ((row & 7) << 3));
}

// ---------- weight transpose: Wt[n][k] = W[k][n] (bf16), 5 matrices of 512x512 ----------
// dtype flag computed in-block from raw bits of l (f32 inputs have garbage-exponent
// low-mantissa halves when read as bf16 pairs -> |x| > 1e4 somewhere).
__global__ __launch_bounds__(1024)
void transw_k(const void* __restrict__ fc1W, const void* __restrict__ convW,
              const u16* __restrict__ lbits, u16* __restrict__ Wt)
{
  __shared__ u16 tile[32][33];
  __shared__ int flagS;
  const int tx = threadIdx.x, ty = threadIdx.y;
  const int flat = ty * 32 + tx;
  if (flat < 64) {
    int bad = 0;
    for (int i = flat; i < 1024; i += 64) {
      float f = b2f(lbits[i]);
      if (!(fabsf(f) <= 1.0e4f)) bad = 1;     // catches NaN too
    }
    int any = __any(bad);
    if (flat == 0) flagS = any;
  }
  __syncthreads();
  const bool f32 = (flagS != 0);
  const int w = blockIdx.z;
  const void* W = (w == 0) ? fc1W : convW;
  const size_t base = (w == 0) ? 0 : (size_t)(w - 1) * 262144;
  const size_t i = base + (size_t)(blockIdx.y * 32 + ty) * 512 + (blockIdx.x * 32 + tx);
  float val = f32 ? ((const float*)W)[i] : b2f(((const u16*)W)[i]);
  tile[ty][tx] = f2b(val);
  __syncthreads();
  const int n_out = blockIdx.x * 32 + ty;
  const int k_out = blockIdx.y * 32 + tx;
  Wt[(size_t)w * 262144 + (size_t)n_out * 512 + k_out] = tile[tx][ty];
}

// ---------- fused per-dialogue GCN kernel ----------
// One block per dialogue (128 blocks x 512 threads = 8 waves, 2M x 4N, wave tile
// 64x128). Node matrix X (120x512 bf16, XOR-swizzled) lives in LDS for the whole
// kernel; fp32 state g lives in the MFMA accumulators (acc[4][8] f32x4 = 128 VGPR).
// W streams from L2 in 32-k chunks, reg-staged (global->VGPR->LDS) with counted
// vmcnt so the next chunk's loads hide under the current chunk's ds_read+MFMA.
// All inter-layer g/gb/agg global traffic from the old multi-kernel chain is gone.

__device__ __forceinline__ void gemm_chunks(f32x4 (&acc)[4][8],
                                            const u16* __restrict__ Wlay,
                                            u16* Xs, u16* Wb, int tid)
{
  const int lane = tid & 63, wave = tid >> 6;
  const int wm = wave >> 2, wn = wave & 3;
  const int quad = lane >> 4, l16 = lane & 15;

  // prologue: chunk 0 -> regs (4 x dwordx4 per thread, coalesced 1KB/wave/inst).
  // Source slot pre-permuted so a linear-ish LDS write yields the swizzled layout
  // the bv reads expect (slot' = slot ^ ((n>>2)&3)).
  uint4 st[4];
#pragma unroll
  for (int q = 0; q < 4; ++q) {
    const int cc = q * 512 + tid;
    const int rw = cc >> 2, sl = cc & 3;
    const int sg = sl ^ ((rw >> 2) & 3);
    st[q] = *(const uint4*)(Wlay + (size_t)rw * 512 + sg * 8);
  }

  for (int kc = 0; kc < 16; ++kc) {
    asm volatile("s_waitcnt vmcnt(0)" ::: "memory");    // chunk kc regs arrived
#pragma unroll
    for (int q = 0; q < 4; ++q) {
      const int cc = q * 512 + tid;
      const int rw = cc >> 2, sl = cc & 3;
      *(uint4*)&Wb[rw * 32 + sl * 8] = st[q];
    }
    asm volatile("s_waitcnt lgkmcnt(0)" ::: "memory");  // writes visible
    __builtin_amdgcn_s_barrier();
    asm volatile("" ::: "memory");
    if (kc < 15) {                                      // issue chunk kc+1 early:
#pragma unroll                                          // hides under reads+MFMA
      for (int q = 0; q < 4; ++q) {
        const int cc = q * 512 + tid;
        const int rw = cc >> 2, sl = cc & 3;
        const int sg = sl ^ ((rw >> 2) & 3);
        st[q] = *(const uint4*)(Wlay + (size_t)rw * 512 + (kc + 1) * 32 + sg * 8);
      }
    }
    bf16x8 af[4];
#pragma unroll
    for (int i = 0; i < 4; ++i) {
      const int row = wm * 64 + i * 16 + l16;
      const int s = kc * 4 + quad;
      af[i] = *(const bf16x8*)&Xs[row * 512 + ((s ^ (row & 7)) << 3)];
    }
    __builtin_amdgcn_s_setprio(1);
#pragma unroll
    for (int jg = 0; jg < 2; ++jg) {
      bf16x8 bv[4];
#pragma unroll
      for (int j = 0; j < 4; ++j) {
        const int n = wn * 128 + (jg * 4 + j) * 16 + l16;
        bv[j] = *(const bf16x8*)&Wb[n * 32 + ((quad ^ ((n >> 2) & 3)) << 3)];
      }
#pragma unroll
      for (int i = 0; i < 4; ++i)
#pragma unroll
        for (int j = 0; j < 4; ++j)
          acc[i][jg * 4 + j] =
              __builtin_amdgcn_mfma_f32_16x16x32_bf16(af[i], bv[j], acc[i][jg * 4 + j], 0, 0, 0);
    }
    __builtin_amdgcn_s_setprio(0);
    __builtin_amdgcn_s_barrier();                       // all waves done reading Wb
    asm volatile("" ::: "memory");
  }
}

__device__ __forceinline__ void bias_add(f32x4 (&acc)[4][8], const void* bptr,
                                         int boff, bool f32io, int tid)
{
  const int lane = tid & 63, wave = tid >> 6;
  const int wn = wave & 3, l16 = lane & 15;
  float breg[8];
#pragma unroll
  for (int j = 0; j < 8; ++j) {
    const int col = wn * 128 + j * 16 + l16;
    breg[j] = f32io ? ((const float*)bptr)[boff + col] : b2f(((const u16*)bptr)[boff + col]);
  }
#pragma unroll
  for (int i = 0; i < 4; ++i)
#pragma unroll
    for (int j = 0; j < 8; ++j)
#pragma unroll
      for (int r = 0; r < 4; ++r)
        acc[i][j][r] += breg[j];
}

__device__ __forceinline__ void x_write(u16* Xs, const f32x4 (&acc)[4][8], int tid)
{
  const int lane = tid & 63, wave = tid >> 6;
  const int wm = wave >> 2, wn = wave & 3;
  const int quad = lane >> 4, l16 = lane & 15;
#pragma unroll
  for (int i = 0; i < 4; ++i)
#pragma unroll
    for (int r = 0; r < 4; ++r) {
      const int row = wm * 64 + i * 16 + quad * 4 + r;
      if (row < 120) {
#pragma unroll
        for (int j = 0; j < 8; ++j) {
          const int col = wn * 128 + j * 16 + l16;
          Xs[xidx(row, col)] = f2b(acc[i][j][r]);
        }
      }
    }
}

// colsum (t-ascending, exactly the old order) + in-place agg; column-private per
// thread (c = tid), so no barrier needed between sum and update.
__device__ __forceinline__ void colsum_agg(u16* Xs, int tid)
{
  const int c = tid;
  float bs0 = 0.f, bs1 = 0.f, bs2 = 0.f;
#pragma unroll 8
  for (int t = 0; t < 40; ++t) bs0 += b2f(Xs[xidx(t, c)]);
#pragma unroll 8
  for (int t = 0; t < 40; ++t) bs1 += b2f(Xs[xidx(40 + t, c)]);
#pragma unroll 8
  for (int t = 0; t < 40; ++t) bs2 += b2f(Xs[xidx(80 + t, c)]);
  const float inv42 = 1.0f / 42.0f;
#pragma unroll 4
  for (int t = 0; t < 40; ++t) {
    const int i0 = xidx(t, c), i1 = xidx(40 + t, c), i2 = xidx(80 + t, c);
    const float x0 = b2f(Xs[i0]), x1 = b2f(Xs[i1]), x2 = b2f(Xs[i2]);
    Xs[i0] = f2b((bs0 + x1 + x2) * inv42);
    Xs[i1] = f2b((bs1 + x0 + x2) * inv42);
    Xs[i2] = f2b((bs2 + x0 + x1) * inv42);
  }
}

__device__ __forceinline__ void writeout(void* outv, const f32x4 (&acc)[4][8],
                                         int d, int cbase, bool f32io, int tid)
{
  const int lane = tid & 63, wave = tid >> 6;
  const int wm = wave >> 2, wn = wave & 3;
  const int quad = lane >> 4, l16 = lane & 15;
#pragma unroll
  for (int i = 0; i < 4; ++i)
#pragma unroll
    for (int r = 0; r < 4; ++r) {
      const int row = wm * 64 + i * 16 + quad * 4 + r;
      if (row < 120) {
        const int mod = row / 40, t = row - mod * 40;
        const size_t base = (size_t)(d * 40 + t) * 4608 + (size_t)mod * 1536 + cbase;
#pragma unroll
        for (int j = 0; j < 8; ++j) {
          const int col = wn * 128 + j * 16 + l16;
          if (f32io) ((float*)outv)[base + col] = acc[i][j][r];
          else       ((u16*)outv)[base + col]  = f2b(acc[i][j][r]);
        }
      }
    }
}

__global__ __launch_bounds__(512, 2)
void fused_k(const void* __restrict__ a, const void* __restrict__ v,
             const void* __restrict__ l, const void* __restrict__ qmask,
             const void* __restrict__ spk, const void* __restrict__ fc1b,
             const void* __restrict__ convb, const u16* __restrict__ Wt,
             void* __restrict__ outv)
{
  // X: 126 rows allocated; rows 0..119 = nodes, 120..125 zeroed (MFMA pad reads
  // rows up to 127 -> rows 126/127 read stale LDS; their garbage lands only in
  // acc rows >=120 which are never stored). Wb: one 512x32 W chunk, slot-swizzled.
  __shared__ __align__(16) u16 Xs[126 * 512];   // 129,024 B
  __shared__ __align__(16) u16 Wb[512 * 32];    //  32,768 B  (total 161,792)
  const int tid = threadIdx.x;
  const int d = blockIdx.x;

  // dtype flag (same test as the old detect_k), broadcast via Xs[0]
  if (tid < 64) {
    int bad = 0;
    const u16* lb = (const u16*)l;
    for (int i = tid; i < 1024; i += 64) {
      float f = b2f(lb[i]);
      if (!(fabsf(f) <= 1.0e4f)) bad = 1;
    }
    int any = __any(bad);
    if (tid == 0) ((int*)Xs)[0] = any;
  }
  __syncthreads();
  const bool f32io = (((int*)Xs)[0] != 0);
  __syncthreads();

  // ---- load phase: feats -> Xs (bf16, swizzled) + d_out cols [0,512)
  {
    const int cs = (tid & 63) * 8;
    const int rg = tid >> 6;
#pragma unroll
    for (int it = 0; it < 15; ++it) {
      const int r = it * 8 + rg;            // 0..119
      const int mod = r / 40, t = r - mod * 40;
      const int u = d * 40 + t;
      float vals[8];
      const void* srcp = (mod == 1) ? a : ((mod == 2) ? v : l);
      load8(srcp, (size_t)u * 512 + cs, f32io, vals);
      if (mod == 0) {
        const int qi = (t * 128 + d) * 2;
        float q0 = f32io ? ((const float*)qmask)[qi]     : b2f(((const u16*)qmask)[qi]);
        float q1 = f32io ? ((const float*)qmask)[qi + 1] : b2f(((const u16*)qmask)[qi + 1]);
        const int sidx = (q1 > q0) ? 1 : 0;
        float sv[8];
        load8(spk, (size_t)sidx * 512 + cs, f32io, sv);
#pragma unroll
        for (int j2 = 0; j2 < 8; ++j2) vals[j2] += sv[j2];
      }
      const size_t oidx = (size_t)u * 4608 + (size_t)mod * 1536 + cs;
      if (f32io) {
        float4* op = (float4*)((float*)outv + oidx);
        op[0] = make_float4(vals[0], vals[1], vals[2], vals[3]);
        op[1] = make_float4(vals[4], vals[5], vals[6], vals[7]);
      } else {
        store8_bf16((u16*)outv, oidx, vals);
      }
      uint32_t w[4];
#pragma unroll
      for (int q = 0; q < 4; ++q)
        w[q] = (uint32_t)f2b(vals[2 * q]) | ((uint32_t)f2b(vals[2 * q + 1]) << 16);
      *(uint4*)&Xs[xidx(r, cs)] = make_uint4(w[0], w[1], w[2], w[3]);
    }
    const int rz = 120 + rg;                 // zero pad rows 120..125
    if (rz < 126) *(uint4*)&Xs[xidx(rz, cs)] = make_uint4(0, 0, 0, 0);
  }
  __syncthreads();

  // ---- layer 0: x1 = feats @ fc1W + fc1b (acc from 0)
  f32x4 acc[4][8];
#pragma unroll
  for (int i = 0; i < 4; ++i)
#pragma unroll
    for (int j = 0; j < 8; ++j) {
      f32x4 z = {0.f, 0.f, 0.f, 0.f};
      acc[i][j] = z;
    }
  gemm_chunks(acc, Wt, Xs, Wb, tid);
  bias_add(acc, fc1b, 0, f32io, tid);
  writeout(outv, acc, d, 512, f32io, tid);   // d_out cols [512,1024) = x1
  __syncthreads();
  x_write(Xs, acc, tid);                     // Xs <- bf16(x1) (= old gb)
  __syncthreads();

  // ---- 4 GCN layers: acc += agg(Xs) @ Wk + bk
#pragma unroll 1
  for (int L = 0; L < 4; ++L) {
    colsum_agg(Xs, tid);
    __syncthreads();
    gemm_chunks(acc, Wt + (size_t)(L + 1) * 262144, Xs, Wb, tid);
    bias_add(acc, convb, L * 512, f32io, tid);
    if (L < 3) {
      __syncthreads();
      x_write(Xs, acc, tid);
      __syncthreads();
    }
  }
  writeout(outv, acc, d, 1024, f32io, tid);  // d_out cols [1024,1536) = gnn_out
}

// ---------- launch ----------
extern "C" void kernel_launch(void* const* d_in, const int* in_sizes, int n_in,
                              void* d_out, int out_size, void* d_ws, size_t ws_size,
                              hipStream_t stream)
{
  const void* a     = d_in[0];
  const void* v     = d_in[1];
  const void* l     = d_in[2];
  const void* qmask = d_in[3];
  const void* spk   = d_in[4];
  const void* fc1W  = d_in[5];
  const void* fc1b  = d_in[6];
  const void* convW = d_in[7];
  const void* convb = d_in[8];

  u16* Wt = (u16*)d_ws;                      // 5*512*512*2 = 2,621,440 B

  // 1) transpose weights (fc1 + 4 conv layers) to N-major bf16; flag computed in-block
  transw_k<<<dim3(16, 16, 5), dim3(32, 32), 0, stream>>>(fc1W, convW, (const u16*)l, Wt);

  // 2) whole per-dialogue pipeline in one persistent kernel (128 blocks = 1/dialogue)
  fused_k<<<128, 512, 0, stream>>>(a, v, l, qmask, spk, fc1b, convb, Wt, d_out);
}

// Round 4
// 353.090 us; speedup vs baseline: 1.3167x; 1.3167x over previous
//
#include <hip/hip_runtime.h>
#include <cstdint>
#include <cstddef>

typedef unsigned short u16;
typedef __attribute__((ext_vector_type(8))) short bf16x8;
typedef __attribute__((ext_vector_type(4))) float f32x4;

// ---------- bf16 helpers ----------
__device__ __forceinline__ float b2f(u16 u) {
  union { uint32_t i; float f; } x; x.i = ((uint32_t)u) << 16; return x.f;
}
__device__ __forceinline__ u16 f2b(float f) {
  union { float f; uint32_t i; } x; x.f = f;
  uint32_t u = x.i;
  u += 0x7fffu + ((u >> 16) & 1u);   // RNE
  return (u16)(u >> 16);
}
__device__ __forceinline__ void store8_bf16(u16* p, size_t idx, const float o[8]) {
  uint32_t w[4];
#pragma unroll
  for (int q = 0; q < 4; q++)
    w[q] = (uint32_t)f2b(o[2 * q]) | ((uint32_t)f2b(o[2 * q + 1]) << 16);
  *(uint4*)(p + idx) = make_uint4(w[0], w[1], w[2], w[3]);
}

// ---------- dtype detect (bf16 vs f32 inputs) from raw bits of l ----------
__global__ __launch_bounds__(64)
void detect_k(const u16* __restrict__ lbits, int* __restrict__ flag)
{
  const int tid = threadIdx.x;
  int bad = 0;
  for (int i = tid; i < 1024; i += 64) {
    float f = b2f(lbits[i]);
    if (!(fabsf(f) <= 1.0e4f)) bad = 1;   // catches NaN too
  }
  int any = __any(bad);
  if (tid == 0) *flag = any ? 1 : 0;
}

// ---------- weight transpose: Wt[n][k] = W[k][n] (bf16), 5 matrices of 512x512 ----------
__global__ __launch_bounds__(1024)
void transw_k(const void* __restrict__ fc1W, const void* __restrict__ convW,
              u16* __restrict__ Wt, const int* __restrict__ flagp)
{
  const bool f32 = (*flagp != 0);
  __shared__ u16 tile[32][33];
  const int w = blockIdx.z;
  const void* W = (w == 0) ? fc1W : convW;
  const size_t base = (w == 0) ? 0 : (size_t)(w - 1) * 262144;
  const int tx = threadIdx.x, ty = threadIdx.y;
  const size_t i = base + (size_t)(blockIdx.y * 32 + ty) * 512 + (blockIdx.x * 32 + tx);
  float val = f32 ? ((const float*)W)[i] : b2f(((const u16*)W)[i]);
  tile[ty][tx] = f2b(val);
  __syncthreads();
  const int n_out = blockIdx.x * 32 + ty;
  const int k_out = blockIdx.y * 32 + tx;
  Wt[(size_t)w * 262144 + (size_t)n_out * 512 + k_out] = tile[tx][ty];
}

// ---------- column sums per (dialogue,modality) block over bf16 gb ----------
__global__ __launch_bounds__(256)
void colsum_k(const u16* __restrict__ gb, float* __restrict__ Bsum)
{
  const int dm = blockIdx.x * 4 + (threadIdx.x >> 6);
  const int c0 = (threadIdx.x & 63) * 8;
  const u16* p = gb + (size_t)dm * 40 * 512 + c0;
  float s[8] = {0.f, 0.f, 0.f, 0.f, 0.f, 0.f, 0.f, 0.f};
#pragma unroll
  for (int t = 0; t < 40; t++) {
    uint4 w = *(const uint4*)(p + (size_t)t * 512);
    uint32_t ww[4] = {w.x, w.y, w.z, w.w};
#pragma unroll
    for (int q = 0; q < 4; q++) {
      s[2 * q]     += b2f((u16)(ww[q] & 0xffffu));
      s[2 * q + 1] += b2f((u16)(ww[q] >> 16));
    }
  }
  float4* bp = (float4*)(Bsum + (size_t)dm * 512 + c0);
  bp[0] = make_float4(s[0], s[1], s[2], s[3]);
  bp[1] = make_float4(s[4], s[5], s[6], s[7]);
}

// ---------- GEMM v4: C = [resid +] A(15360x512,bf16) @ Bt^T + bias ----------
// A is never materialized: staged in registers per 32-k chunk, either from the
// raw inputs (MODE0: feats = src[+spk], also writes d_out cols [0,512)) or from
// gb+Bsum (MODEG: agg = (Bsum+gb[n1]+gb[n2])/42). Bit-identical f32->bf16 math
// to the old feats_k/aggfuse_k. 512 thr, 8 waves (2Mx4N), 128x128 tile, BK=32,
// double-buffered LDS with ONE __syncthreads per chunk; loads for chunk kk+2
// are issued AFTER the barrier so its implicit vmcnt(0) drain never waits them.
// Fragment tiles slot-XOR swizzled (slot ^= row&3) to cut ds_read_b128 bank
// conflicts from ~8-way to ~4-way. XCD-bijective 480-block swizzle kept.

#define ISSUE_LOADS(KK)                                                         \
  {                                                                             \
    const size_t off_ = (size_t)(KK) * 32 + c8;                                 \
    if (MODEG) {                                                                \
      rG1 = *(const uint4*)(gbA + p1 + off_);                                   \
      rG2 = *(const uint4*)(gbA + p2 + off_);                                   \
      rB0 = *(const float4*)(BsumP + bsb + off_);                               \
      rB1 = *(const float4*)(BsumP + bsb + off_ + 4);                           \
    } else if (f32io) {                                                         \
      const float* sp_ = (const float*)srcRow + srcBase + off_;                 \
      rF0 = *(const float4*)sp_;  rF1 = *(const float4*)(sp_ + 4);              \
      if (addspk) {                                                             \
        const float* pp_ = (const float*)spk + spkOff + off_;                   \
        rS0 = *(const float4*)pp_;  rS1 = *(const float4*)(pp_ + 4);            \
      }                                                                         \
    } else {                                                                    \
      rU = *(const uint4*)((const u16*)srcRow + srcBase + off_);                \
      if (addspk) rSu = *(const uint4*)((const u16*)spk + spkOff + off_);       \
    }                                                                           \
    rBt = *(const uint4*)(Bt + browB + (size_t)(KK) * 32);                      \
  }

#define FINISH_WRITE(KK, CUR)                                                   \
  {                                                                             \
    float aval[8];                                                              \
    if (MODEG) {                                                                \
      uint32_t w1_[4] = {rG1.x, rG1.y, rG1.z, rG1.w};                           \
      uint32_t w2_[4] = {rG2.x, rG2.y, rG2.z, rG2.w};                           \
      float bs_[8] = {rB0.x, rB0.y, rB0.z, rB0.w, rB1.x, rB1.y, rB1.z, rB1.w};  \
      const float inv42_ = 1.0f / 42.0f;                                        \
      _Pragma("unroll")                                                         \
      for (int q = 0; q < 4; ++q) {                                             \
        aval[2*q]   = (bs_[2*q]   + b2f((u16)(w1_[q] & 0xffffu))                \
                                  + b2f((u16)(w2_[q] & 0xffffu))) * inv42_;     \
        aval[2*q+1] = (bs_[2*q+1] + b2f((u16)(w1_[q] >> 16))                    \
                                  + b2f((u16)(w2_[q] >> 16)))     * inv42_;     \
      }                                                                         \
    } else {                                                                    \
      if (f32io) {                                                              \
        aval[0]=rF0.x; aval[1]=rF0.y; aval[2]=rF0.z; aval[3]=rF0.w;             \
        aval[4]=rF1.x; aval[5]=rF1.y; aval[6]=rF1.z; aval[7]=rF1.w;             \
        if (addspk) {                                                           \
          aval[0]+=rS0.x; aval[1]+=rS0.y; aval[2]+=rS0.z; aval[3]+=rS0.w;       \
          aval[4]+=rS1.x; aval[5]+=rS1.y; aval[6]+=rS1.z; aval[7]+=rS1.w;       \
        }                                                                       \
      } else {                                                                  \
        uint32_t wu_[4] = {rU.x, rU.y, rU.z, rU.w};                             \
        _Pragma("unroll")                                                       \
        for (int q = 0; q < 4; ++q) {                                           \
          aval[2*q]   = b2f((u16)(wu_[q] & 0xffffu));                           \
          aval[2*q+1] = b2f((u16)(wu_[q] >> 16));                               \
        }                                                                       \
        if (addspk) {                                                           \
          uint32_t ws_[4] = {rSu.x, rSu.y, rSu.z, rSu.w};                       \
          _Pragma("unroll")                                                     \
          for (int q = 0; q < 4; ++q) {                                         \
            aval[2*q]   += b2f((u16)(ws_[q] & 0xffffu));                        \
            aval[2*q+1] += b2f((u16)(ws_[q] >> 16));                            \
          }                                                                     \
        }                                                                       \
      }                                                                         \
      if (dow0) {                                                               \
        const size_t o_ = d0base + (size_t)(KK) * 32 + c8;                      \
        if (f32io) {                                                            \
          float4* op_ = (float4*)((float*)Dout0 + o_);                          \
          op_[0] = make_float4(aval[0], aval[1], aval[2], aval[3]);             \
          op_[1] = make_float4(aval[4], aval[5], aval[6], aval[7]);             \
        } else {                                                                \
          store8_bf16((u16*)Dout0, o_, aval);                                   \
        }                                                                       \
      }                                                                         \
    }                                                                           \
    uint32_t wp_[4];                                                            \
    _Pragma("unroll")                                                           \
    for (int q = 0; q < 4; ++q)                                                 \
      wp_[q] = (uint32_t)f2b(aval[2*q]) | ((uint32_t)f2b(aval[2*q+1]) << 16);   \
    *(uint4*)&As[CUR][r0 * 32 + ((cslot ^ (r0 & 3)) << 3)] =                    \
        make_uint4(wp_[0], wp_[1], wp_[2], wp_[3]);                             \
    *(uint4*)&Bs2[CUR][r0 * 32 + ((cslot ^ (r0 & 3)) << 3)] = rBt;              \
  }

template<bool MODEG>
__global__ __launch_bounds__(512, 4)
void gemm_f(const void* __restrict__ a, const void* __restrict__ v,
            const void* __restrict__ l, const void* __restrict__ qmask,
            const void* __restrict__ spk,
            const u16* __restrict__ gbA, const float* __restrict__ BsumP,
            const u16* __restrict__ Bt,
            const void* __restrict__ bias, int boff,
            const float* __restrict__ resid,
            float* __restrict__ Cg, u16* __restrict__ Cgb,
            void* __restrict__ Cout, int outoff,
            void* __restrict__ Dout0,
            const int* __restrict__ flagp)
{
  const bool f32io = (*flagp != 0);
  __shared__ __align__(16) u16 As[2][128 * 32];
  __shared__ __align__(16) u16 Bs2[2][128 * 32];
  const int tid  = threadIdx.x;
  const int lane = tid & 63;
  const int wave = tid >> 6;
  const int wm = wave >> 2;
  const int wn = wave & 3;
  const int quad = lane >> 4;
  const int l16  = lane & 15;

  // XCD-bijective swizzle: 480 = 8 XCD x 60 chunks, N-tile fastest inside a chunk
  const int lin = blockIdx.x;
  const int wg  = (lin & 7) * 60 + (lin >> 3);
  const int tileM = (wg >> 2) * 128;
  const int tileN = (wg & 3) * 128;

  // ---- staging geometry: thread owns row r0, k-slot cslot of each chunk
  const int r0 = tid >> 2, cslot = tid & 3, c8 = cslot * 8;
  const int gm = tileM + r0;
  const int dmRow = gm / 40, tRow = gm - dmRow * 40;
  const int modRow = dmRow % 3, dRow = dmRow / 3;
  const int uRow = dRow * 40 + tRow;

  // MODE0 metadata
  const void* srcRow = (modRow == 1) ? a : ((modRow == 2) ? v : l);
  const bool addspk = (!MODEG) && (modRow == 0);
  size_t spkOff = 0;
  if (addspk) {
    const int qi = (tRow * 128 + dRow) * 2;
    float q0 = f32io ? ((const float*)qmask)[qi]     : b2f(((const u16*)qmask)[qi]);
    float q1 = f32io ? ((const float*)qmask)[qi + 1] : b2f(((const u16*)qmask)[qi + 1]);
    spkOff = (q1 > q0) ? 512 : 0;          // np.argmax tie -> first index
  }
  const bool dow0 = (!MODEG) && (tileN == 0);
  const size_t srcBase = (size_t)uRow * 512;
  const size_t d0base  = (size_t)uRow * 4608 + (size_t)modRow * 1536;

  // MODEG metadata (agg = (Bsum + gb[n1] + gb[n2]) / 42, rows fixed per thread)
  const int m1 = (modRow == 0) ? 1 : 0;
  const int m2 = (modRow == 2) ? 1 : 2;
  const int d3 = dmRow - modRow;
  const size_t p1  = ((size_t)(d3 + m1) * 40 + tRow) * 512;
  const size_t p2  = ((size_t)(d3 + m2) * 40 + tRow) * 512;
  const size_t bsb = (size_t)dmRow * 512;

  const size_t browB = (size_t)(tileN + r0) * 512 + c8;

  // stage registers
  float4 rF0, rF1, rS0, rS1;   // MODE0 f32 inputs
  uint4  rU, rSu;              // MODE0 bf16 inputs
  uint4  rG1, rG2;             // MODEG gb rows
  float4 rB0, rB1;             // MODEG Bsum
  uint4  rBt;                  // B (Wt) chunk

  f32x4 acc[4][2];
#pragma unroll
  for (int i = 0; i < 4; i++)
#pragma unroll
    for (int j = 0; j < 2; j++) {
      f32x4 z = {0.f, 0.f, 0.f, 0.f};
      acc[i][j] = z;
    }

  // prologue: chunk 0 staged + visible, chunk 1 loads in flight
  ISSUE_LOADS(0);
  FINISH_WRITE(0, 0);
  __syncthreads();
  ISSUE_LOADS(1);

  for (int kk = 0; kk < 16; ++kk) {
    const int cur = kk & 1;
    bf16x8 af[4], bv[2];
#pragma unroll
    for (int i = 0; i < 4; i++) {
      const int row = wm * 64 + i * 16 + l16;
      af[i] = *(const bf16x8*)&As[cur][row * 32 + ((quad ^ (row & 3)) << 3)];
    }
#pragma unroll
    for (int j = 0; j < 2; j++) {
      const int rowB = wn * 32 + j * 16 + l16;
      bv[j] = *(const bf16x8*)&Bs2[cur][rowB * 32 + ((quad ^ (rowB & 3)) << 3)];
    }
    __builtin_amdgcn_s_setprio(1);
#pragma unroll
    for (int i = 0; i < 4; i++)
#pragma unroll
      for (int j = 0; j < 2; j++)
        acc[i][j] = __builtin_amdgcn_mfma_f32_16x16x32_bf16(af[i], bv[j], acc[i][j], 0, 0, 0);
    __builtin_amdgcn_s_setprio(0);
    if (kk < 15) {
      FINISH_WRITE(kk + 1, cur ^ 1);   // compiler waits the in-flight loads here
      __syncthreads();                 // drains; nothing else in flight by design
      if (kk < 14) ISSUE_LOADS(kk + 2);
    }
  }

  // epilogue: C/D layout col = lane&15, row = quad*4 + reg
#pragma unroll
  for (int i = 0; i < 4; i++) {
    const int gmBase = tileM + wm * 64 + i * 16 + quad * 4;
#pragma unroll
    for (int r = 0; r < 4; r++) {
      const int gmE = gmBase + r;
      size_t outRow = 0;
      if (Cout != nullptr) {
        int dd = gmE / 120, md = gmE - dd * 120, mm = md / 40, tt = md - mm * 40;
        outRow = (size_t)(dd * 40 + tt) * 4608 + mm * 1536 + outoff;
      }
#pragma unroll
      for (int j = 0; j < 2; j++) {
        const int gn = tileN + wn * 32 + j * 16 + l16;
        float bval = f32io ? ((const float*)bias)[boff + gn] : b2f(((const u16*)bias)[boff + gn]);
        float vsum = acc[i][j][r] + bval;
        if (resid != nullptr) vsum += resid[(size_t)gmE * 512 + gn];
        if (Cg  != nullptr) Cg[(size_t)gmE * 512 + gn] = vsum;
        if (Cgb != nullptr) Cgb[(size_t)gmE * 512 + gn] = f2b(vsum);
        if (Cout != nullptr) {
          if (f32io) ((float*)Cout)[outRow + gn] = vsum;
          else       ((u16*)Cout)[outRow + gn] = f2b(vsum);
        }
      }
    }
  }
}

// ---------- launch ----------
extern "C" void kernel_launch(void* const* d_in, const int* in_sizes, int n_in,
                              void* d_out, int out_size, void* d_ws, size_t ws_size,
                              hipStream_t stream)
{
  const void* a     = d_in[0];
  const void* v     = d_in[1];
  const void* l     = d_in[2];
  const void* qmask = d_in[3];
  const void* spk   = d_in[4];
  const void* fc1W  = d_in[5];
  const void* fc1b  = d_in[6];
  const void* convW = d_in[7];
  const void* convb = d_in[8];

  char* ws = (char*)d_ws;
  u16*   Wt   = (u16*)(ws);                       // 5*512*512*2   =  2,621,440 B
  float* g    = (float*)(ws + 2621440);           // 15360*512*4   = 31,457,280 B
  u16*   gb   = (u16*)(ws + 34078720);            // 15360*512*2   = 15,728,640 B
  float* Bsum = (float*)(ws + 49807360);          // 384*512*4     =    786,432 B
  int*   flag = (int*)(ws + 50593792);            // 4 B ; total ~50.6 MB

  // 0) detect input dtype (bf16 vs f32) from raw bits of l
  detect_k<<<1, 64, 0, stream>>>((const u16*)l, flag);

  // 1) transpose weights (fc1 + 4 conv layers) to N-major bf16
  transw_k<<<dim3(16, 16, 5), dim3(32, 32), 0, stream>>>(fc1W, convW, Wt, flag);

  // 2) x1 = feats @ fc1W + fc1b, feats staged in-register from raw inputs;
  //    writes d_out cols [0,512) (feats) + [512,1024) (x1), g (f32), gb (bf16)
  gemm_f<false><<<480, 512, 0, stream>>>(a, v, l, qmask, spk,
                                         nullptr, nullptr, Wt, fc1b, 0, nullptr,
                                         g, gb, d_out, 512, d_out, flag);

  // 3) four GCN layers: g += agg(gb) @ Wk + bk, agg staged in-register from gb+Bsum
  for (int k = 0; k < 4; k++) {
    colsum_k<<<96, 256, 0, stream>>>(gb, Bsum);
    const bool last = (k == 3);
    gemm_f<true><<<480, 512, 0, stream>>>(nullptr, nullptr, nullptr, nullptr, nullptr,
                                          gb, Bsum, Wt + (size_t)(k + 1) * 262144,
                                          convb, k * 512,
                                          g, last ? nullptr : g, last ? nullptr : gb,
                                          last ? d_out : nullptr, 1024, nullptr, flag);
  }
}

// Round 5
// 336.444 us; speedup vs baseline: 1.3818x; 1.0495x over previous
//
#include <hip/hip_runtime.h>
#include <cstdint>
#include <cstddef>

typedef unsigned short u16;
typedef __attribute__((ext_vector_type(8))) short bf16x8;
typedef __attribute__((ext_vector_type(4))) float f32x4;

// ---------- bf16 helpers ----------
__device__ __forceinline__ float b2f(u16 u) {
  union { uint32_t i; float f; } x; x.i = ((uint32_t)u) << 16; return x.f;
}
__device__ __forceinline__ u16 f2b(float f) {
  union { float f; uint32_t i; } x; x.f = f;
  uint32_t u = x.i;
  u += 0x7fffu + ((u >> 16) & 1u);   // RNE
  return (u16)(u >> 16);
}
__device__ __forceinline__ void store8_bf16(u16* p, size_t idx, const float o[8]) {
  uint32_t w[4];
#pragma unroll
  for (int q = 0; q < 4; q++)
    w[q] = (uint32_t)f2b(o[2 * q]) | ((uint32_t)f2b(o[2 * q + 1]) << 16);
  *(uint4*)(p + idx) = make_uint4(w[0], w[1], w[2], w[3]);
}

// ---------- per-block dtype detect (bf16 vs f32) from raw bits of l ----------
// wave 0 scans 1024 u16; broadcast via LDS. Same predicate as the old detect_k.
__device__ __forceinline__ bool detect_f32(const u16* lb, int* ldsflag, int tid) {
  if (tid < 64) {
    int bad = 0;
    for (int i = tid; i < 1024; i += 64) {
      float f = b2f(lb[i]);
      if (!(fabsf(f) <= 1.0e4f)) bad = 1;   // catches NaN too
    }
    int any = __any(bad);
    if (tid == 0) *ldsflag = any;
  }
  __syncthreads();
  const bool r = (*ldsflag != 0);
  __syncthreads();
  return r;
}

// ---------- weight transpose: Wt[n][k] = W[k][n] (bf16), 5 matrices of 512x512 ----------
// 480 blocks x 512 threads; each block walks 32x32 tiles (<=3 per block).
__global__ __launch_bounds__(512)
void transw_k(const void* __restrict__ fc1W, const void* __restrict__ convW,
              const u16* __restrict__ lbits, u16* __restrict__ Wt)
{
  __shared__ u16 tile[32][33];
  __shared__ int flagS;
  const int tid = threadIdx.x;
  const bool f32 = detect_f32(lbits, &flagS, tid);
  const int tx = tid & 31, ty0 = tid >> 5;         // ty0 0..15
  for (int tl = blockIdx.x; tl < 1280; tl += 480) {
    const int w = tl >> 8, rem = tl & 255;
    const int by = rem >> 4, bx = rem & 15;
    const void* W = (w == 0) ? fc1W : convW;
    const size_t base = (w == 0) ? 0 : (size_t)(w - 1) * 262144;
#pragma unroll
    for (int half = 0; half < 2; ++half) {
      const int ty = ty0 + half * 16;
      const size_t i = base + (size_t)(by * 32 + ty) * 512 + (bx * 32 + tx);
      float val = f32 ? ((const float*)W)[i] : b2f(((const u16*)W)[i]);
      tile[ty][tx] = f2b(val);
    }
    __syncthreads();
#pragma unroll
    for (int half = 0; half < 2; ++half) {
      const int ty = ty0 + half * 16;
      const int n_out = bx * 32 + ty, k_out = by * 32 + tx;
      Wt[(size_t)w * 262144 + (size_t)n_out * 512 + k_out] = tile[tx][ty];
    }
    __syncthreads();
  }
}

// ---------- GEMM v5 ----------
// As r4's gemm_f (reg-staged A/B chunks, 128x128 tile, 8 waves, XCD swizzle,
// single __syncthreads per chunk, slot-XOR LDS swizzle) plus:
//  * colsum fused: the 4 (dialogue,modality) column-sum groups this tile needs
//    are computed into LDS at phase start (t-ascending order -> bit-identical),
//    overlapped with the chunk-0 global loads. No more colsum_k dispatches.
//  * gb ping-pong (gbIn read-only, Cgb writes the other buffer) -> removes the
//    cross-tile read/write race r4 had (absmax 0.084 -> deterministic 0.0625).
//  * vectorized epilogue: acc staged through a padded LDS tile (64x132 f32,
//    2 halves, aliasing the dead As/Bs buffers) so every thread owns one row
//    x16 contiguous cols -> float4/uint4 resid loads + g/gb/out stores instead
//    of ~100 scalar VMEM per thread.

#define ISSUE_LOADS(KK)                                                         \
  {                                                                             \
    const size_t off_ = (size_t)(KK) * 32 + c8;                                 \
    if (MODEG) {                                                                \
      rG1 = *(const uint4*)(gbIn + p1 + off_);                                  \
      rG2 = *(const uint4*)(gbIn + p2 + off_);                                  \
    } else if (f32io) {                                                         \
      const float* sp_ = (const float*)srcRow + srcBase + off_;                 \
      rF0 = *(const float4*)sp_;  rF1 = *(const float4*)(sp_ + 4);              \
      if (addspk) {                                                             \
        const float* pp_ = (const float*)spk + spkOff + off_;                   \
        rS0 = *(const float4*)pp_;  rS1 = *(const float4*)(pp_ + 4);            \
      }                                                                         \
    } else {                                                                    \
      rU = *(const uint4*)((const u16*)srcRow + srcBase + off_);                \
      if (addspk) rSu = *(const uint4*)((const u16*)spk + spkOff + off_);       \
    }                                                                           \
    rBt = *(const uint4*)(Bt + browB + (size_t)(KK) * 32);                      \
  }

#define FINISH_WRITE(KK, CUR)                                                   \
  {                                                                             \
    float aval[8];                                                              \
    if (MODEG) {                                                                \
      const size_t off_ = (size_t)(KK) * 32 + c8;                               \
      uint32_t w1_[4] = {rG1.x, rG1.y, rG1.z, rG1.w};                           \
      uint32_t w2_[4] = {rG2.x, rG2.y, rG2.z, rG2.w};                           \
      float bs_[8];                                                             \
      *(float4*)&bs_[0] = *(const float4*)&BsumL[bsrow * 512 + off_];           \
      *(float4*)&bs_[4] = *(const float4*)&BsumL[bsrow * 512 + off_ + 4];       \
      const float inv42_ = 1.0f / 42.0f;                                        \
      _Pragma("unroll")                                                         \
      for (int q = 0; q < 4; ++q) {                                             \
        aval[2*q]   = (bs_[2*q]   + b2f((u16)(w1_[q] & 0xffffu))                \
                                  + b2f((u16)(w2_[q] & 0xffffu))) * inv42_;     \
        aval[2*q+1] = (bs_[2*q+1] + b2f((u16)(w1_[q] >> 16))                    \
                                  + b2f((u16)(w2_[q] >> 16)))     * inv42_;     \
      }                                                                         \
    } else {                                                                    \
      if (f32io) {                                                              \
        aval[0]=rF0.x; aval[1]=rF0.y; aval[2]=rF0.z; aval[3]=rF0.w;             \
        aval[4]=rF1.x; aval[5]=rF1.y; aval[6]=rF1.z; aval[7]=rF1.w;             \
        if (addspk) {                                                           \
          aval[0]+=rS0.x; aval[1]+=rS0.y; aval[2]+=rS0.z; aval[3]+=rS0.w;       \
          aval[4]+=rS1.x; aval[5]+=rS1.y; aval[6]+=rS1.z; aval[7]+=rS1.w;       \
        }                                                                       \
      } else {                                                                  \
        uint32_t wu_[4] = {rU.x, rU.y, rU.z, rU.w};                             \
        _Pragma("unroll")                                                       \
        for (int q = 0; q < 4; ++q) {                                           \
          aval[2*q]   = b2f((u16)(wu_[q] & 0xffffu));                           \
          aval[2*q+1] = b2f((u16)(wu_[q] >> 16));                               \
        }                                                                       \
        if (addspk) {                                                           \
          uint32_t ws_[4] = {rSu.x, rSu.y, rSu.z, rSu.w};                       \
          _Pragma("unroll")                                                     \
          for (int q = 0; q < 4; ++q) {                                         \
            aval[2*q]   += b2f((u16)(ws_[q] & 0xffffu));                        \
            aval[2*q+1] += b2f((u16)(ws_[q] >> 16));                            \
          }                                                                     \
        }                                                                       \
      }                                                                         \
      if (dow0) {                                                               \
        const size_t o_ = d0base + (size_t)(KK) * 32 + c8;                      \
        if (f32io) {                                                            \
          float4* op_ = (float4*)((float*)Dout0 + o_);                          \
          op_[0] = make_float4(aval[0], aval[1], aval[2], aval[3]);             \
          op_[1] = make_float4(aval[4], aval[5], aval[6], aval[7]);             \
        } else {                                                                \
          store8_bf16((u16*)Dout0, o_, aval);                                   \
        }                                                                       \
      }                                                                         \
    }                                                                           \
    uint32_t wp_[4];                                                            \
    _Pragma("unroll")                                                           \
    for (int q = 0; q < 4; ++q)                                                 \
      wp_[q] = (uint32_t)f2b(aval[2*q]) | ((uint32_t)f2b(aval[2*q+1]) << 16);   \
    *(uint4*)&AsB[(CUR) * 4096 + r0 * 32 + ((cslot ^ (r0 & 3)) << 3)] =         \
        make_uint4(wp_[0], wp_[1], wp_[2], wp_[3]);                             \
    *(uint4*)&BsB[(CUR) * 4096 + r0 * 32 + ((cslot ^ (r0 & 3)) << 3)] = rBt;    \
  }

template<bool MODEG>
__global__ __launch_bounds__(512, 4)
void gemm_f(const void* __restrict__ a, const void* __restrict__ v,
            const void* __restrict__ l, const void* __restrict__ qmask,
            const void* __restrict__ spk,
            const u16* __restrict__ gbIn, const u16* __restrict__ Bt,
            const void* __restrict__ bias, int boff,
            const float* __restrict__ resid,
            float* __restrict__ Cg, u16* __restrict__ Cgb,
            void* __restrict__ Cout, int outoff,
            void* __restrict__ Dout0)
{
  // LDS map: [0,16384) As[2][4096] u16 ; [16384,32768) Bs[2][4096] u16 ;
  // EP (epilogue, 64x132 f32 = 33792 B) aliases [0,33792) after the K-loop;
  // BsumL [4][512] f32 at [33792,41984) lives through the K-loop (MODEG).
  __shared__ __align__(16) char LB[33792 + 8192];
  u16*   AsB   = (u16*)LB;
  u16*   BsB   = (u16*)(LB + 16384);
  float* EP    = (float*)LB;
  float* BsumL = (float*)(LB + 33792);
  __shared__ int flagS;

  const int tid  = threadIdx.x;
  const bool f32io = detect_f32((const u16*)l, &flagS, tid);

  const int lane = tid & 63;
  const int wave = tid >> 6;
  const int wm = wave >> 2;
  const int wn = wave & 3;
  const int quad = lane >> 4;
  const int l16  = lane & 15;

  // XCD-bijective swizzle: 480 = 8 XCD x 60 chunks, N-tile fastest in a chunk
  const int lin = blockIdx.x;
  const int wg  = (lin & 7) * 60 + (lin >> 3);
  const int tileM = (wg >> 2) * 128;
  const int tileN = (wg & 3) * 128;

  // staging geometry: thread owns row r0, k-slot cslot of each 32-k chunk
  const int r0 = tid >> 2, cslot = tid & 3, c8 = cslot * 8;
  const int gm = tileM + r0;
  const int dmRow = gm / 40, tRow = gm - dmRow * 40;
  const int modRow = dmRow % 3, dRow = dmRow / 3;
  const int uRow = dRow * 40 + tRow;
  const int dm0 = tileM / 40;             // first dm group this tile touches
  const int bsrow = dmRow - dm0;          // 0..3

  // MODE0 metadata
  const void* srcRow = (modRow == 1) ? a : ((modRow == 2) ? v : l);
  const bool addspk = (!MODEG) && (modRow == 0);
  size_t spkOff = 0;
  if (addspk) {
    const int qi = (tRow * 128 + dRow) * 2;
    float q0 = f32io ? ((const float*)qmask)[qi]     : b2f(((const u16*)qmask)[qi]);
    float q1 = f32io ? ((const float*)qmask)[qi + 1] : b2f(((const u16*)qmask)[qi + 1]);
    spkOff = (q1 > q0) ? 512 : 0;          // np.argmax tie -> first index
  }
  const bool dow0 = (!MODEG) && (tileN == 0);
  const size_t srcBase = (size_t)uRow * 512;
  const size_t d0base  = (size_t)uRow * 4608 + (size_t)modRow * 1536;

  // MODEG metadata (agg = (Bsum + gb[n1] + gb[n2]) / 42)
  const int m1 = (modRow == 0) ? 1 : 0;
  const int m2 = (modRow == 2) ? 1 : 2;
  const int d3 = dmRow - modRow;
  const size_t p1 = ((size_t)(d3 + m1) * 40 + tRow) * 512;
  const size_t p2 = ((size_t)(d3 + m2) * 40 + tRow) * 512;

  const size_t browB = (size_t)(tileN + r0) * 512 + c8;

  // stage registers
  float4 rF0, rF1, rS0, rS1;   // MODE0 f32 inputs
  uint4  rU, rSu;              // MODE0 bf16 inputs
  uint4  rG1, rG2;             // MODEG gb rows
  uint4  rBt;                  // B (Wt) chunk

  f32x4 acc[4][2];
#pragma unroll
  for (int i = 0; i < 4; i++)
#pragma unroll
    for (int j = 0; j < 2; j++) {
      f32x4 z = {0.f, 0.f, 0.f, 0.f};
      acc[i][j] = z;
    }

  // prologue: chunk-0 loads in flight while the block computes its 4 column-sum
  // groups (t-ascending -> bit-identical to the old colsum_k).
  ISSUE_LOADS(0);
  if (MODEG) {
#pragma unroll
    for (int g = 0; g < 4; ++g) {
      const u16* colp = gbIn + (size_t)(dm0 + g) * 40 * 512 + tid;
      float s = 0.f;
#pragma unroll 8
      for (int t = 0; t < 40; ++t) s += b2f(colp[t * 512]);
      BsumL[g * 512 + tid] = s;
    }
  }
  __syncthreads();                        // BsumL visible to all
  FINISH_WRITE(0, 0);
  __syncthreads();
  ISSUE_LOADS(1);

  for (int kk = 0; kk < 16; ++kk) {
    const int cur = kk & 1;
    bf16x8 af[4], bv[2];
#pragma unroll
    for (int i = 0; i < 4; i++) {
      const int row = wm * 64 + i * 16 + l16;
      af[i] = *(const bf16x8*)&AsB[cur * 4096 + row * 32 + ((quad ^ (row & 3)) << 3)];
    }
#pragma unroll
    for (int j = 0; j < 2; j++) {
      const int rowB = wn * 32 + j * 16 + l16;
      bv[j] = *(const bf16x8*)&BsB[cur * 4096 + rowB * 32 + ((quad ^ (rowB & 3)) << 3)];
    }
    __builtin_amdgcn_s_setprio(1);
#pragma unroll
    for (int i = 0; i < 4; i++)
#pragma unroll
      for (int j = 0; j < 2; j++)
        acc[i][j] = __builtin_amdgcn_mfma_f32_16x16x32_bf16(af[i], bv[j], acc[i][j], 0, 0, 0);
    __builtin_amdgcn_s_setprio(0);
    if (kk < 15) {
      FINISH_WRITE(kk + 1, cur ^ 1);
      __syncthreads();
      if (kk < 14) ISSUE_LOADS(kk + 2);
    }
  }

  // ---- vectorized epilogue: acc -> LDS (64x132 f32, 2 halves) -> wide I/O ----
  // C/D layout: row = wm*64 + i*16 + quad*4 + r, col = wn*32 + j*16 + l16.
  // Half h covers i in {2h,2h+1} (rows wm*64+32h .. +32). Values identical to
  // r4: vsum = acc + bias, then += resid, then f2b.
  __syncthreads();                        // everyone done reading As/Bs (EP alias)
  const int erl = tid >> 3;               // 0..63: local row
  const int ec0 = (tid & 7) * 16;         // col base
#pragma unroll
  for (int h = 0; h < 2; ++h) {
    if (h) __syncthreads();               // reads of half 0 done before overwrite
#pragma unroll
    for (int ii = 0; ii < 2; ++ii) {
      const int i = 2 * h + ii;
#pragma unroll
      for (int j = 0; j < 2; ++j)
#pragma unroll
        for (int r = 0; r < 4; ++r)
          EP[(wm * 32 + ii * 16 + quad * 4 + r) * 132 + wn * 32 + j * 16 + l16] =
              acc[i][j][r];
    }
    __syncthreads();
    const int gr = tileM + (erl >> 5) * 64 + 32 * h + (erl & 31);
    size_t outRow = 0;
    if (Cout != nullptr) {
      const int dd = gr / 120, md = gr - dd * 120, mm = md / 40, tt = md - mm * 40;
      outRow = (size_t)(dd * 40 + tt) * 4608 + (size_t)mm * 1536 + outoff;
    }
#pragma unroll
    for (int G = 0; G < 2; ++G) {
      const int gc = ec0 + G * 8;
      const int gn = tileN + gc;
      float ev[8];
      *(float4*)&ev[0] = *(const float4*)&EP[erl * 132 + gc];
      *(float4*)&ev[4] = *(const float4*)&EP[erl * 132 + gc + 4];
      float vsum[8];
      if (f32io) {
        const float* bp = (const float*)bias + boff + gn;
        float4 b0 = *(const float4*)bp, b1 = *(const float4*)(bp + 4);
        const float bb[8] = {b0.x, b0.y, b0.z, b0.w, b1.x, b1.y, b1.z, b1.w};
#pragma unroll
        for (int q = 0; q < 8; ++q) vsum[q] = ev[q] + bb[q];
      } else {
        uint4 bu = *(const uint4*)((const u16*)bias + boff + gn);
        uint32_t bw[4] = {bu.x, bu.y, bu.z, bu.w};
#pragma unroll
        for (int q = 0; q < 4; ++q) {
          vsum[2*q]   = ev[2*q]   + b2f((u16)(bw[q] & 0xffffu));
          vsum[2*q+1] = ev[2*q+1] + b2f((u16)(bw[q] >> 16));
        }
      }
      if (resid != nullptr) {
        const float* rp = resid + (size_t)gr * 512 + gn;
        float4 r0v = *(const float4*)rp, r1v = *(const float4*)(rp + 4);
        const float rr[8] = {r0v.x, r0v.y, r0v.z, r0v.w, r1v.x, r1v.y, r1v.z, r1v.w};
#pragma unroll
        for (int q = 0; q < 8; ++q) vsum[q] += rr[q];
      }
      if (Cg != nullptr) {
        float* cp = Cg + (size_t)gr * 512 + gn;
        *(float4*)cp       = make_float4(vsum[0], vsum[1], vsum[2], vsum[3]);
        *(float4*)(cp + 4) = make_float4(vsum[4], vsum[5], vsum[6], vsum[7]);
      }
      if (Cgb != nullptr) store8_bf16(Cgb, (size_t)gr * 512 + gn, vsum);
      if (Cout != nullptr) {
        if (f32io) {
          float* op = (float*)Cout + outRow + gn;
          *(float4*)op       = make_float4(vsum[0], vsum[1], vsum[2], vsum[3]);
          *(float4*)(op + 4) = make_float4(vsum[4], vsum[5], vsum[6], vsum[7]);
        } else {
          store8_bf16((u16*)Cout, outRow + gn, vsum);
        }
      }
    }
  }
}

// ---------- launch ----------
extern "C" void kernel_launch(void* const* d_in, const int* in_sizes, int n_in,
                              void* d_out, int out_size, void* d_ws, size_t ws_size,
                              hipStream_t stream)
{
  const void* a     = d_in[0];
  const void* v     = d_in[1];
  const void* l     = d_in[2];
  const void* qmask = d_in[3];
  const void* spk   = d_in[4];
  const void* fc1W  = d_in[5];
  const void* fc1b  = d_in[6];
  const void* convW = d_in[7];
  const void* convb = d_in[8];

  char* ws = (char*)d_ws;
  u16*   Wt  = (u16*)(ws);                        // 5*512*512*2 =  2,621,440 B
  float* g   = (float*)(ws + 2621440);            // 15360*512*4 = 31,457,280 B
  u16*   gbA = (u16*)(ws + 34078720);             // 15360*512*2 = 15,728,640 B
  u16*   gbB = (u16*)(ws + 49807360);             // 15360*512*2 = 15,728,640 B
                                                  // total ~65.5 MB

  // 1) transpose weights (flag detect folded in)
  transw_k<<<480, 512, 0, stream>>>(fc1W, convW, (const u16*)l, Wt);

  // 2) layer 0: x1 = feats @ fc1W + fc1b ; feats staged in-register from inputs;
  //    writes d_out cols [0,512) (feats) + [512,1024) (x1), g (f32), gbA (bf16)
  gemm_f<false><<<480, 512, 0, stream>>>(a, v, l, qmask, spk,
                                         nullptr, Wt, fc1b, 0,
                                         nullptr, g, gbA, d_out, 512, d_out);

  // 3) four GCN layers: g += agg(gb) @ Wk + bk ; colsum fused in-block;
  //    gb ping-pong (read one buffer, write the other) -> no cross-tile race.
  const u16* gin[4]  = {gbA, gbB, gbA, gbB};
  u16*       gout[4] = {gbB, gbA, gbB, nullptr};
  for (int k = 0; k < 4; k++) {
    const bool last = (k == 3);
    gemm_f<true><<<480, 512, 0, stream>>>(nullptr, nullptr, l, nullptr, nullptr,
                                          gin[k], Wt + (size_t)(k + 1) * 262144,
                                          convb, k * 512,
                                          g, last ? nullptr : g, gout[k],
                                          last ? d_out : nullptr, 1024, nullptr);
  }
}